// Round 12
// baseline (168.846 us; speedup 1.0000x reference)
//
#include <hip/hip_runtime.h>
#include <hip/hip_bf16.h>

// Inputs: 0 features[N,64] f32 | 1 receivers[E] i32 | 2 relpos[E,2] f32
//         3 window_support[1] f32 | 4 senders[E] i32 | 5 kernel[4,2,64,64] f32
//         6 bias[64] f32   -> out [N,64] f32

#define T_TAPS 16
#define BUCKET 64   // max edges per receiver (Poisson(16): P(deg>64) ~ 1e-20)

typedef unsigned short u16;
typedef short s16x8 __attribute__((ext_vector_type(8)));
typedef u16 u16x8 __attribute__((ext_vector_type(8)));
typedef float f32x2 __attribute__((ext_vector_type(2)));
typedef float f32x4 __attribute__((ext_vector_type(4)));

static __device__ __forceinline__ u16 f2bf(float x) {
    union { float f; unsigned u; } v; v.f = x;
    unsigned r = v.u + 0x7FFF + ((v.u >> 16) & 1);
    return (u16)(r >> 16);
}

// ---------------- setup: KfT build + zero(cnt) in one launch ----------------
// KfT[o][k], k = i*16 + t ; t=x*4+y ; y<2: +kern[x][y][i][o] ; else -kern[3-x][3-y][i][o]
__global__ __launch_bounds__(256) void ascc_setup(
    u16* __restrict__ KfT, const float* __restrict__ kern,
    int* __restrict__ cnt, int Nn)
{
    int b = blockIdx.x;
    if (b < 256) {
        int idx = b * 256 + threadIdx.x;   // 64*1024
        int o = idx >> 10;
        int k = idx & 1023;
        int i = k >> 4, t = k & 15;
        int x = t >> 2, y = t & 3;
        float val;
        if (y < 2) val =  kern[(((x * 2 + y) * 64) + i) * 64 + o];
        else       val = -kern[((((3 - x) * 2 + (3 - y)) * 64) + i) * 64 + o];
        KfT[(size_t)o * 1024 + k] = f2bf(val);
    } else {
        int i = (b - 256) * 256 + threadIdx.x;
        if (i < Nn) cnt[i] = 0;
    }
}

// ---------- fillprep: claim bucket slot, write one 32-B record --------------
// rec[2*(r*BUCKET+p)]   = (wx0,wx1,wx2,wx3) * win
// rec[2*(r*BUCKET+p)+1] = (wy0,wy1,wy2, bitcast(sender)); wy3 = 1-wy0-wy1-wy2
__global__ __launch_bounds__(256) void ascc_fillprep(
    float4* __restrict__ rec,
    int* __restrict__ cnt, const int* __restrict__ receivers,
    const float* __restrict__ relpos, const float* __restrict__ wsup,
    const int* __restrict__ senders, int E)
{
    int e = blockIdx.x * 256 + threadIdx.x;
    if (e >= E) return;
    int r = receivers[e];
    int p = atomicAdd(&cnt[r], 1);
    if (p >= BUCKET) return;   // statistically unreachable

    float ws = wsup[0];
    float2 rp = *(const float2*)(relpos + 2 * e);
    float u0 = fminf(fmaxf(rp.x / ws, -1.f), 1.f);
    float u1 = fminf(fmaxf(rp.y / ws, -1.f), 1.f);
    float gx = (u0 + 1.f) * 1.5f;
    float gy = (u1 + 1.f) * 1.5f;
    float x0f = fminf(fmaxf(floorf(gx), 0.f), 2.f);
    float y0f = fminf(fmaxf(floorf(gy), 0.f), 2.f);
    float fx = gx - x0f, fy = gy - y0f;
    int x0i = (int)x0f, y0i = (int)y0f;
    float r2 = u0 * u0 + u1 * u1;
    float win = fmaxf(1.f - r2, 0.f);
    win = win * win * win;
    float wx[4], wy[4];
    #pragma unroll
    for (int k = 0; k < 4; ++k)
        wx[k] = win * ((k == x0i) ? (1.f - fx) : ((k == x0i + 1) ? fx : 0.f));
    #pragma unroll
    for (int k = 0; k < 4; ++k)
        wy[k] = (k == y0i) ? (1.f - fy) : ((k == y0i + 1) ? fy : 0.f);

    union { int i; float f; } sv; sv.i = senders[e];
    size_t slot = (size_t)r * BUCKET + p;
    rec[2 * slot]     = make_float4(wx[0], wx[1], wx[2], wx[3]);
    rec[2 * slot + 1] = make_float4(wy[0], wy[1], wy[2], sv.f);
}

// ---------- FUSED accum + mini-GEMM: 16 waves, ONE receiver per wave --------
// Phase 1: wave w accumulates receiver n0+w with the R11-proven inner loop
// (4-deep masked groups, packed f32x2), writes bf16 row to XOR-swizzled LDS
// A[16][1024] (32 KB). 1024-thr blocks -> 2 blocks/CU = 32 waves/CU of gather
// parallelism (MORE than the split accum's ~19).
// Phase 2 (after one barrier): waves 0..3 run the R10-verified MFMA phase:
// 16x64 out tile, K=1024, B-frags straight from L2-resident KfT.
__global__ __launch_bounds__(1024) void ascc_fused(
    float* __restrict__ out,
    const float* __restrict__ features,
    const int* __restrict__ cnt,
    const float4* __restrict__ rec,
    const u16* __restrict__ KfT,
    const float* __restrict__ bias,
    int Nn)
{
    __shared__ u16 Al[16 * 1024];   // 32 KB, row stride 2048 B, XOR-swizzled

    const int tid  = threadIdx.x;
    const int lane = tid & 63;
    const int w    = tid >> 6;       // 0..15 = wave = receiver row
    const int n0   = blockIdx.x * 16;
    const int row  = w;
    const int r    = n0 + row;
    const int sw   = (row & 7) << 4;
    char* lbase = (char*)Al + row * 2048;

    // ---------------- phase 1: one receiver per wave ----------------
    if (r >= Nn) {
        u16x8 z = {0, 0, 0, 0, 0, 0, 0, 0};
        *(u16x8*)(lbase + ((lane * 32) ^ sw)) = z;
        *(u16x8*)(lbase + ((lane * 32 + 16) ^ sw)) = z;
    } else {
        f32x2 acc[8];   // [tx*2 + p], p pairs ty {0,1} and {2,3}
        #pragma unroll
        for (int t = 0; t < 8; ++t) acc[t] = (f32x2){0.f, 0.f};

        int n = cnt[r];
        n = (n < BUCKET) ? n : BUCKET;
        const float4* rbase = rec + (size_t)r * (2 * BUCKET);

        #pragma unroll 1
        for (int j = 0; j < n; j += 4) {
            float4 ra[4], rb[4];
            float g[4];
            #pragma unroll
            for (int q = 0; q < 4; ++q) {
                int jj = j + q;
                int jc = (jj < n) ? jj : (n - 1);
                ra[q] = rbase[2 * jc];
                rb[q] = rbase[2 * jc + 1];
            }
            #pragma unroll
            for (int q = 0; q < 4; ++q) {
                union { float f; int i; } sv; sv.f = rb[q].w;
                float gg = features[(size_t)sv.i * 64 + lane];
                g[q] = (j + q < n) ? gg : 0.f;
            }
            #pragma unroll
            for (int q = 0; q < 4; ++q) {
                float wy3 = 1.f - rb[q].x - rb[q].y - rb[q].z;
                f32x2 wyg01 = {rb[q].x * g[q], rb[q].y * g[q]};
                f32x2 wyg23 = {rb[q].z * g[q], wy3 * g[q]};
                float wxa[4] = {ra[q].x, ra[q].y, ra[q].z, ra[q].w};
                #pragma unroll
                for (int tx = 0; tx < 4; ++tx) {
                    acc[tx * 2]     += wxa[tx] * wyg01;
                    acc[tx * 2 + 1] += wxa[tx] * wyg23;
                }
            }
        }

        // tap t = tx*4+ty ; value = acc[tx*2 + (ty>>1)][ty&1]
        u16x8 lo, hi;
        #pragma unroll
        for (int t = 0; t < 8; ++t)  lo[t] = f2bf(acc[(t >> 2) * 2 + ((t & 3) >> 1)][t & 1]);
        #pragma unroll
        for (int t = 0; t < 8; ++t)  hi[t] = f2bf(acc[(2 + (t >> 2)) * 2 + ((t & 3) >> 1)][t & 1]);
        // LDS row `row`, k = ch*16 + tap (bf16): byte = lane*32 + tap*2, XOR-swz
        *(u16x8*)(lbase + ((lane * 32) ^ sw)) = lo;
        *(u16x8*)(lbase + ((lane * 32 + 16) ^ sw)) = hi;
    }

    __syncthreads();

    // ---------------- phase 2: waves 0..3 do [16x1024]x[1024x16] ----------
    if (w < 4) {
        const int arow  = lane & 15;
        const int asw   = (arow & 7) << 4;
        const char* ab  = (const char*)Al + arow * 2048;
        const int kfrag = (lane >> 4) << 3;                 // k sub-offset (elems)
        const u16* bptr = KfT + (size_t)((w << 4) + (lane & 15)) * 1024 + kfrag;

        f32x4 c0 = {}, c1 = {};
        #pragma unroll
        for (int kc = 0; kc < 1024; kc += 64) {
            int kb0 = (kc + kfrag) << 1;
            int kb1 = (kc + 32 + kfrag) << 1;
            s16x8 af0 = *(const s16x8*)(ab + (kb0 ^ asw));
            s16x8 af1 = *(const s16x8*)(ab + (kb1 ^ asw));
            s16x8 bf0 = *(const s16x8*)(bptr + kc);
            s16x8 bf1 = *(const s16x8*)(bptr + kc + 32);
            c0 = __builtin_amdgcn_mfma_f32_16x16x32_bf16(af0, bf0, c0, 0, 0, 0);
            c1 = __builtin_amdgcn_mfma_f32_16x16x32_bf16(af1, bf1, c1, 0, 0, 0);
        }

        // D row = (lane>>4)*4 + reg -> receiver; col = w*16 + (lane&15)
        const int col = (w << 4) + (lane & 15);
        const float bv = bias[col];
        const int drow = (lane >> 4) << 2;
        #pragma unroll
        for (int reg = 0; reg < 4; ++reg) {
            int nn = n0 + drow + reg;
            if (nn < Nn) out[(size_t)nn * 64 + col] = c0[reg] + c1[reg] + bv;
        }
    }
}

extern "C" void kernel_launch(void* const* d_in, const int* in_sizes, int n_in,
                              void* d_out, int out_size, void* d_ws, size_t ws_size,
                              hipStream_t stream) {
    const float* features  = (const float*)d_in[0];
    const int*   receivers = (const int*)d_in[1];
    const float* relpos    = (const float*)d_in[2];
    const float* wsup      = (const float*)d_in[3];
    const int*   senders   = (const int*)d_in[4];
    const float* kern      = (const float*)d_in[5];
    const float* bias      = (const float*)d_in[6];
    float* out = (float*)d_out;

    const int Nn = in_sizes[0] / 64;
    const int E  = in_sizes[1];

    // ws: cnt[N] | rec[N*BUCKET*2 float4] | KfT
    char* wp = (char*)d_ws;
    size_t p = 0;
    auto take = [&](size_t bytes) { char* q = wp + p; p = (p + bytes + 255) & ~(size_t)255; return q; };
    int*    cnt = (int*)take((size_t)Nn * 4);
    float4* rec = (float4*)take((size_t)Nn * BUCKET * 32);
    u16*    KfT = (u16*)take((size_t)64 * 1024 * 2);
    (void)ws_size;

    ascc_setup<<<dim3(256 + (Nn + 255) / 256), dim3(256), 0, stream>>>(KfT, kern, cnt, Nn);
    ascc_fillprep<<<dim3((E + 255) / 256), dim3(256), 0, stream>>>(
        rec, cnt, receivers, relpos, wsup, senders, E);
    ascc_fused<<<dim3((Nn + 15) / 16), dim3(1024), 0, stream>>>(
        out, features, cnt, rec, KfT, bias, Nn);
}

// Round 13
// 145.934 us; speedup vs baseline: 1.1570x; 1.1570x over previous
//
#include <hip/hip_runtime.h>
#include <hip/hip_bf16.h>

// Inputs: 0 features[N,64] f32 | 1 receivers[E] i32 | 2 relpos[E,2] f32
//         3 window_support[1] f32 | 4 senders[E] i32 | 5 kernel[4,2,64,64] f32
//         6 bias[64] f32   -> out [N,64] f32

#define T_TAPS 16
#define BUCKET 64   // max edges per receiver (Poisson(16): P(deg>64) ~ 1e-20)

typedef unsigned short u16;
typedef short s16x8 __attribute__((ext_vector_type(8)));
typedef u16 u16x8 __attribute__((ext_vector_type(8)));
typedef float f32x2 __attribute__((ext_vector_type(2)));
typedef float f32x4 __attribute__((ext_vector_type(4)));

static __device__ __forceinline__ u16 f2bf(float x) {
    union { float f; unsigned u; } v; v.f = x;
    unsigned r = v.u + 0x7FFF + ((v.u >> 16) & 1);
    return (u16)(r >> 16);
}

// ---------------- setup: KfT build + zero(cnt) in one launch ----------------
// KfT[o][k], k = i*16 + t ; t=x*4+y ; y<2: +kern[x][y][i][o] ; else -kern[3-x][3-y][i][o]
__global__ __launch_bounds__(256) void ascc_setup(
    u16* __restrict__ KfT, const float* __restrict__ kern,
    int* __restrict__ cnt, int Nn)
{
    int b = blockIdx.x;
    if (b < 256) {
        int idx = b * 256 + threadIdx.x;   // 64*1024
        int o = idx >> 10;
        int k = idx & 1023;
        int i = k >> 4, t = k & 15;
        int x = t >> 2, y = t & 3;
        float val;
        if (y < 2) val =  kern[(((x * 2 + y) * 64) + i) * 64 + o];
        else       val = -kern[((((3 - x) * 2 + (3 - y)) * 64) + i) * 64 + o];
        KfT[(size_t)o * 1024 + k] = f2bf(val);
    } else {
        int i = (b - 256) * 256 + threadIdx.x;
        if (i < Nn) cnt[i] = 0;
    }
}

// ---------- fillprep: claim bucket slot, write one 32-B record --------------
// rec[2*(r*BUCKET+p)]   = (wx0,wx1,wx2,wx3) * win
// rec[2*(r*BUCKET+p)+1] = (wy0,wy1,wy2, bitcast(sender)); wy3 = 1-wy0-wy1-wy2
__global__ __launch_bounds__(256) void ascc_fillprep(
    float4* __restrict__ rec,
    int* __restrict__ cnt, const int* __restrict__ receivers,
    const float* __restrict__ relpos, const float* __restrict__ wsup,
    const int* __restrict__ senders, int E)
{
    int e = blockIdx.x * 256 + threadIdx.x;
    if (e >= E) return;
    int r = receivers[e];
    int p = atomicAdd(&cnt[r], 1);
    if (p >= BUCKET) return;   // statistically unreachable

    float ws = wsup[0];
    float2 rp = *(const float2*)(relpos + 2 * e);
    float u0 = fminf(fmaxf(rp.x / ws, -1.f), 1.f);
    float u1 = fminf(fmaxf(rp.y / ws, -1.f), 1.f);
    float gx = (u0 + 1.f) * 1.5f;
    float gy = (u1 + 1.f) * 1.5f;
    float x0f = fminf(fmaxf(floorf(gx), 0.f), 2.f);
    float y0f = fminf(fmaxf(floorf(gy), 0.f), 2.f);
    float fx = gx - x0f, fy = gy - y0f;
    int x0i = (int)x0f, y0i = (int)y0f;
    float r2 = u0 * u0 + u1 * u1;
    float win = fmaxf(1.f - r2, 0.f);
    win = win * win * win;
    float wx[4], wy[4];
    #pragma unroll
    for (int k = 0; k < 4; ++k)
        wx[k] = win * ((k == x0i) ? (1.f - fx) : ((k == x0i + 1) ? fx : 0.f));
    #pragma unroll
    for (int k = 0; k < 4; ++k)
        wy[k] = (k == y0i) ? (1.f - fy) : ((k == y0i + 1) ? fy : 0.f);

    union { int i; float f; } sv; sv.i = senders[e];
    size_t slot = (size_t)r * BUCKET + p;
    rec[2 * slot]     = make_float4(wx[0], wx[1], wx[2], wx[3]);
    rec[2 * slot + 1] = make_float4(wy[0], wy[1], wy[2], sv.f);
}

// ---------------- Phase 1: per-receiver register accumulation -> bf16 A -----
// one wave per receiver; lane = channel; 4-deep masked groups + 2-stage
// record-prefetch pipeline (records for group j+1 load under group j's
// gather latency). Packed f32x2 tap accumulation (v_pk_fma_f32).
// A layout: k = ch*16 + tap  -> lane's 16 taps contiguous, 2x u16x8 stores.
__global__ __launch_bounds__(256) void ascc_accum(
    u16* __restrict__ Abf,
    const float* __restrict__ features,
    const int* __restrict__ cnt,
    const float4* __restrict__ rec,
    int Nn)
{
    int lane = threadIdx.x & 63;
    int r = blockIdx.x * 4 + (threadIdx.x >> 6);
    if (r >= Nn) return;

    f32x2 acc[8];   // [tx*2 + p], p pairs ty {0,1} and {2,3}
    #pragma unroll
    for (int t = 0; t < 8; ++t) acc[t] = (f32x2){0.f, 0.f};

    int n = cnt[r];
    n = (n < BUCKET) ? n : BUCKET;
    const float4* rbase = rec + (size_t)r * (2 * BUCKET);

    // prologue: records for group 0
    float4 ra[4], rb[4];
    #pragma unroll
    for (int q = 0; q < 4; ++q) {
        int jc = (q < n) ? q : (n - 1);
        ra[q] = rbase[2 * jc];
        rb[q] = rbase[2 * jc + 1];
    }

    #pragma unroll 1
    for (int j = 0; j < n; j += 4) {
        // 1) issue gathers for current group (depend only on rb already in regs)
        float g[4];
        #pragma unroll
        for (int q = 0; q < 4; ++q) {
            union { float f; int i; } sv; sv.f = rb[q].w;
            float gg = features[(size_t)sv.i * 64 + lane];
            g[q] = (j + q < n) ? gg : 0.f;
        }
        // 2) prefetch next group's records (independent -> overlap gather latency)
        float4 na[4], nb[4];
        #pragma unroll
        for (int q = 0; q < 4; ++q) {
            int jj = j + 4 + q;
            int jc = (jj < n) ? jj : (n - 1);
            na[q] = rbase[2 * jc];
            nb[q] = rbase[2 * jc + 1];
        }
        // 3) compute current group
        #pragma unroll
        for (int q = 0; q < 4; ++q) {
            float wy3 = 1.f - rb[q].x - rb[q].y - rb[q].z;
            f32x2 wyg01 = {rb[q].x * g[q], rb[q].y * g[q]};
            f32x2 wyg23 = {rb[q].z * g[q], wy3 * g[q]};
            float wxa[4] = {ra[q].x, ra[q].y, ra[q].z, ra[q].w};
            #pragma unroll
            for (int tx = 0; tx < 4; ++tx) {
                acc[tx * 2]     += wxa[tx] * wyg01;
                acc[tx * 2 + 1] += wxa[tx] * wyg23;
            }
        }
        // 4) rotate
        #pragma unroll
        for (int q = 0; q < 4; ++q) { ra[q] = na[q]; rb[q] = nb[q]; }
    }

    // tap t = tx*4+ty ; value = acc[tx*2 + (ty>>1)][ty&1]
    // lo: taps 0..7 (tx = 0..1) ; hi: taps 8..15 (tx = 2..3)
    u16x8 lo, hi;
    #pragma unroll
    for (int t = 0; t < 8; ++t)  lo[t] = f2bf(acc[(t >> 2) * 2 + ((t & 3) >> 1)][t & 1]);
    #pragma unroll
    for (int t = 0; t < 8; ++t)  hi[t] = f2bf(acc[(2 + (t >> 2)) * 2 + ((t & 3) >> 1)][t & 1]);
    u16* base = Abf + (size_t)r * 1024 + lane * 16;
    *(u16x8*)base = lo;
    *(u16x8*)(base + 8) = hi;
}

// ---------------- Phase 2: MFMA GEMM out[N,64] = A[N,1024] * Kf[1024,64] ----
__global__ __launch_bounds__(256) void ascc_mgemm(
    float* __restrict__ out,
    const u16* __restrict__ Abf,
    const u16* __restrict__ KfT,
    const float* __restrict__ bias,
    int Nn)
{
    __shared__ u16 Al[64 * 128];
    __shared__ u16 Bl[64 * 128];

    const int tid = threadIdx.x;
    const int lane = tid & 63;
    const int w = tid >> 6;
    const int n0 = blockIdx.x * 64;

    f32x4 acc[4] = {};

    for (int kc = 0; kc < 1024; kc += 128) {
        __syncthreads();
        {
            int row = tid >> 2, seg = tid & 3;
            int n = n0 + row;
            const u16* src = Abf + (size_t)n * 1024 + kc + seg * 32;
            char* dst = (char*)Al + row * 256;
            u16x8 z = {0, 0, 0, 0, 0, 0, 0, 0};
            #pragma unroll
            for (int g2 = 0; g2 < 4; ++g2) {
                u16x8 v = (n < Nn) ? *(const u16x8*)(src + g2 * 8) : z;
                int colb = seg * 64 + g2 * 16;
                *(u16x8*)(dst + (colb ^ ((row & 7) << 4))) = v;
            }
        }
        {
            int row = tid >> 2, seg = tid & 3;
            const u16* src = KfT + (size_t)row * 1024 + kc + seg * 32;
            char* dst = (char*)Bl + row * 256;
            #pragma unroll
            for (int g2 = 0; g2 < 4; ++g2) {
                u16x8 v = *(const u16x8*)(src + g2 * 8);
                int colb = seg * 64 + g2 * 16;
                *(u16x8*)(dst + (colb ^ ((row & 7) << 4))) = v;
            }
        }
        __syncthreads();
        int wr = w << 4;
        #pragma unroll
        for (int ks = 0; ks < 4; ++ks) {
            int arow = wr + (lane & 15);
            int kb = ks * 64 + ((lane >> 4) << 4);
            s16x8 af = *(const s16x8*)((char*)Al + arow * 256 + (kb ^ ((arow & 7) << 4)));
            #pragma unroll
            for (int t = 0; t < 4; ++t) {
                int brow = (t << 4) + (lane & 15);
                s16x8 bf = *(const s16x8*)((char*)Bl + brow * 256 + (kb ^ ((brow & 7) << 4)));
                acc[t] = __builtin_amdgcn_mfma_f32_16x16x32_bf16(af, bf, acc[t], 0, 0, 0);
            }
        }
    }

    int rbase = n0 + (w << 4) + ((lane >> 4) << 2);
    #pragma unroll
    for (int t = 0; t < 4; ++t) {
        int col = (t << 4) + (lane & 15);
        float bv = bias[col];
        #pragma unroll
        for (int reg = 0; reg < 4; ++reg) {
            int n = rbase + reg;
            if (n < Nn) out[(size_t)n * 64 + col] = acc[t][reg] + bv;
        }
    }
}

extern "C" void kernel_launch(void* const* d_in, const int* in_sizes, int n_in,
                              void* d_out, int out_size, void* d_ws, size_t ws_size,
                              hipStream_t stream) {
    const float* features  = (const float*)d_in[0];
    const int*   receivers = (const int*)d_in[1];
    const float* relpos    = (const float*)d_in[2];
    const float* wsup      = (const float*)d_in[3];
    const int*   senders   = (const int*)d_in[4];
    const float* kern      = (const float*)d_in[5];
    const float* bias      = (const float*)d_in[6];
    float* out = (float*)d_out;

    const int Nn = in_sizes[0] / 64;
    const int E  = in_sizes[1];

    // ws: cnt[N] | rec[N*BUCKET*2 float4] | KfT | Abf
    char* wp = (char*)d_ws;
    size_t p = 0;
    auto take = [&](size_t bytes) { char* q = wp + p; p = (p + bytes + 255) & ~(size_t)255; return q; };
    int*    cnt = (int*)take((size_t)Nn * 4);
    float4* rec = (float4*)take((size_t)Nn * BUCKET * 32);
    u16*    KfT = (u16*)take((size_t)64 * 1024 * 2);
    u16*    Abf = (u16*)take((size_t)Nn * 1024 * 2);
    (void)ws_size;

    ascc_setup<<<dim3(256 + (Nn + 255) / 256), dim3(256), 0, stream>>>(KfT, kern, cnt, Nn);
    ascc_fillprep<<<dim3((E + 255) / 256), dim3(256), 0, stream>>>(
        rec, cnt, receivers, relpos, wsup, senders, E);
    ascc_accum<<<dim3((Nn + 3) / 4), dim3(256), 0, stream>>>(
        Abf, features, cnt, rec, Nn);
    ascc_mgemm<<<dim3((Nn + 63) / 64), dim3(256), 0, stream>>>(
        out, Abf, KfT, bias, Nn);
}

// Round 14
// 136.153 us; speedup vs baseline: 1.2401x; 1.0718x over previous
//
#include <hip/hip_runtime.h>
#include <hip/hip_bf16.h>

// Inputs: 0 features[N,64] f32 | 1 receivers[E] i32 | 2 relpos[E,2] f32
//         3 window_support[1] f32 | 4 senders[E] i32 | 5 kernel[4,2,64,64] f32
//         6 bias[64] f32   -> out [N,64] f32

#define T_TAPS 16
#define BUCKET 64   // max edges per receiver (Poisson(16): P(deg>64) ~ 1e-20)

typedef unsigned short u16;
typedef short s16x8 __attribute__((ext_vector_type(8)));
typedef u16 u16x8 __attribute__((ext_vector_type(8)));
typedef float f32x2 __attribute__((ext_vector_type(2)));
typedef float f32x4 __attribute__((ext_vector_type(4)));

static __device__ __forceinline__ u16 f2bf(float x) {
    union { float f; unsigned u; } v; v.f = x;
    unsigned r = v.u + 0x7FFF + ((v.u >> 16) & 1);
    return (u16)(r >> 16);
}

// ---------------- setup: KfT build + zero(cnt) in one launch ----------------
// KfT[o][k], k = i*16 + t ; t=x*4+y ; y<2: +kern[x][y][i][o] ; else -kern[3-x][3-y][i][o]
__global__ __launch_bounds__(256) void ascc_setup(
    u16* __restrict__ KfT, const float* __restrict__ kern,
    int* __restrict__ cnt, int Nn)
{
    int b = blockIdx.x;
    if (b < 256) {
        int idx = b * 256 + threadIdx.x;   // 64*1024
        int o = idx >> 10;
        int k = idx & 1023;
        int i = k >> 4, t = k & 15;
        int x = t >> 2, y = t & 3;
        float val;
        if (y < 2) val =  kern[(((x * 2 + y) * 64) + i) * 64 + o];
        else       val = -kern[((((3 - x) * 2 + (3 - y)) * 64) + i) * 64 + o];
        KfT[(size_t)o * 1024 + k] = f2bf(val);
    } else {
        int i = (b - 256) * 256 + threadIdx.x;
        if (i < Nn) cnt[i] = 0;
    }
}

// ---------- fillprep: claim bucket slot, write one 32-B record --------------
// rec[2*(r*BUCKET+p)]   = (wx0,wx1,wx2,wx3) * win
// rec[2*(r*BUCKET+p)+1] = (wy0,wy1,wy2, bitcast(sender)); wy3 = 1-wy0-wy1-wy2
__global__ __launch_bounds__(256) void ascc_fillprep(
    float4* __restrict__ rec,
    int* __restrict__ cnt, const int* __restrict__ receivers,
    const float* __restrict__ relpos, const float* __restrict__ wsup,
    const int* __restrict__ senders, int E)
{
    int e = blockIdx.x * 256 + threadIdx.x;
    if (e >= E) return;
    int r = receivers[e];
    int p = atomicAdd(&cnt[r], 1);
    if (p >= BUCKET) return;   // statistically unreachable

    float ws = wsup[0];
    float2 rp = *(const float2*)(relpos + 2 * e);
    float u0 = fminf(fmaxf(rp.x / ws, -1.f), 1.f);
    float u1 = fminf(fmaxf(rp.y / ws, -1.f), 1.f);
    float gx = (u0 + 1.f) * 1.5f;
    float gy = (u1 + 1.f) * 1.5f;
    float x0f = fminf(fmaxf(floorf(gx), 0.f), 2.f);
    float y0f = fminf(fmaxf(floorf(gy), 0.f), 2.f);
    float fx = gx - x0f, fy = gy - y0f;
    int x0i = (int)x0f, y0i = (int)y0f;
    float r2 = u0 * u0 + u1 * u1;
    float win = fmaxf(1.f - r2, 0.f);
    win = win * win * win;
    float wx[4], wy[4];
    #pragma unroll
    for (int k = 0; k < 4; ++k)
        wx[k] = win * ((k == x0i) ? (1.f - fx) : ((k == x0i + 1) ? fx : 0.f));
    #pragma unroll
    for (int k = 0; k < 4; ++k)
        wy[k] = (k == y0i) ? (1.f - fy) : ((k == y0i + 1) ? fy : 0.f);

    union { int i; float f; } sv; sv.i = senders[e];
    size_t slot = (size_t)r * BUCKET + p;
    rec[2 * slot]     = make_float4(wx[0], wx[1], wx[2], wx[3]);
    rec[2 * slot + 1] = make_float4(wy[0], wy[1], wy[2], sv.f);
}

// ---------------- Phase 1: per-receiver register accumulation -> bf16 A -----
// one wave per receiver; lane = channel; 4-deep masked groups.
// Wave-uniformity made explicit via readfirstlane -> record/cnt loads promote
// to the scalar pipe (s_load, SGPR storage, SALU addressing); feature gather
// uses 32-bit indexing (no 64-bit mad chain). Packed f32x2 tap accumulation.
// A layout: k = ch*16 + tap  -> lane's 16 taps contiguous, 2x u16x8 stores.
__global__ __launch_bounds__(256) void ascc_accum(
    u16* __restrict__ Abf,
    const float* __restrict__ features,
    const int* __restrict__ cnt,
    const float4* __restrict__ rec,
    int Nn)
{
    int lane = threadIdx.x & 63;
    int rv = blockIdx.x * 4 + (threadIdx.x >> 6);
    if (rv >= Nn) return;
    const int r = __builtin_amdgcn_readfirstlane(rv);   // wave-uniform receiver

    f32x2 acc[8];   // [tx*2 + p], p pairs ty {0,1} and {2,3}
    #pragma unroll
    for (int t = 0; t < 8; ++t) acc[t] = (f32x2){0.f, 0.f};

    int n = cnt[r];
    n = (n < BUCKET) ? n : BUCKET;
    const float4* rbase = rec + (size_t)r * (2 * BUCKET);

    #pragma unroll 1
    for (int j = 0; j < n; j += 4) {
        // wave-uniform record loads (scalar pipe)
        float4 ra[4], rb[4];
        #pragma unroll
        for (int q = 0; q < 4; ++q) {
            int jj = j + q;
            int jc = (jj < n) ? jj : (n - 1);
            ra[q] = rbase[2 * jc];
            rb[q] = rbase[2 * jc + 1];
        }
        // per-lane feature gathers, 32-bit indexing
        float g[4];
        #pragma unroll
        for (int q = 0; q < 4; ++q) {
            int s = __float_as_int(rb[q].w);
            float gg = features[s * 64 + lane];
            g[q] = (j + q < n) ? gg : 0.f;
        }
        #pragma unroll
        for (int q = 0; q < 4; ++q) {
            float wy3 = 1.f - rb[q].x - rb[q].y - rb[q].z;
            f32x2 wyg01 = {rb[q].x * g[q], rb[q].y * g[q]};
            f32x2 wyg23 = {rb[q].z * g[q], wy3 * g[q]};
            #pragma unroll
            for (int tx = 0; tx < 4; ++tx) {
                float wxa = (tx == 0) ? ra[q].x : (tx == 1) ? ra[q].y
                          : (tx == 2) ? ra[q].z : ra[q].w;
                acc[tx * 2]     += wxa * wyg01;
                acc[tx * 2 + 1] += wxa * wyg23;
            }
        }
    }

    // tap t = tx*4+ty ; value = acc[tx*2 + (ty>>1)][ty&1]
    // lo: taps 0..7 (tx = 0..1) ; hi: taps 8..15 (tx = 2..3)
    u16x8 lo, hi;
    #pragma unroll
    for (int t = 0; t < 8; ++t)  lo[t] = f2bf(acc[(t >> 2) * 2 + ((t & 3) >> 1)][t & 1]);
    #pragma unroll
    for (int t = 0; t < 8; ++t)  hi[t] = f2bf(acc[(2 + (t >> 2)) * 2 + ((t & 3) >> 1)][t & 1]);
    u16* base = Abf + (size_t)r * 1024 + lane * 16;
    *(u16x8*)base = lo;
    *(u16x8*)(base + 8) = hi;
}

// ---------------- Phase 2: MFMA GEMM out[N,64] = A[N,1024] * Kf[1024,64] ----
__global__ __launch_bounds__(256) void ascc_mgemm(
    float* __restrict__ out,
    const u16* __restrict__ Abf,
    const u16* __restrict__ KfT,
    const float* __restrict__ bias,
    int Nn)
{
    __shared__ u16 Al[64 * 128];
    __shared__ u16 Bl[64 * 128];

    const int tid = threadIdx.x;
    const int lane = tid & 63;
    const int w = tid >> 6;
    const int n0 = blockIdx.x * 64;

    f32x4 acc[4] = {};

    for (int kc = 0; kc < 1024; kc += 128) {
        __syncthreads();
        {
            int row = tid >> 2, seg = tid & 3;
            int n = n0 + row;
            const u16* src = Abf + (size_t)n * 1024 + kc + seg * 32;
            char* dst = (char*)Al + row * 256;
            u16x8 z = {0, 0, 0, 0, 0, 0, 0, 0};
            #pragma unroll
            for (int g2 = 0; g2 < 4; ++g2) {
                u16x8 v = (n < Nn) ? *(const u16x8*)(src + g2 * 8) : z;
                int colb = seg * 64 + g2 * 16;
                *(u16x8*)(dst + (colb ^ ((row & 7) << 4))) = v;
            }
        }
        {
            int row = tid >> 2, seg = tid & 3;
            const u16* src = KfT + (size_t)row * 1024 + kc + seg * 32;
            char* dst = (char*)Bl + row * 256;
            #pragma unroll
            for (int g2 = 0; g2 < 4; ++g2) {
                u16x8 v = *(const u16x8*)(src + g2 * 8);
                int colb = seg * 64 + g2 * 16;
                *(u16x8*)(dst + (colb ^ ((row & 7) << 4))) = v;
            }
        }
        __syncthreads();
        int wr = w << 4;
        #pragma unroll
        for (int ks = 0; ks < 4; ++ks) {
            int arow = wr + (lane & 15);
            int kb = ks * 64 + ((lane >> 4) << 4);
            s16x8 af = *(const s16x8*)((char*)Al + arow * 256 + (kb ^ ((arow & 7) << 4)));
            #pragma unroll
            for (int t = 0; t < 4; ++t) {
                int brow = (t << 4) + (lane & 15);
                s16x8 bf = *(const s16x8*)((char*)Bl + brow * 256 + (kb ^ ((brow & 7) << 4)));
                acc[t] = __builtin_amdgcn_mfma_f32_16x16x32_bf16(af, bf, acc[t], 0, 0, 0);
            }
        }
    }

    int rbase = n0 + (w << 4) + ((lane >> 4) << 2);
    #pragma unroll
    for (int t = 0; t < 4; ++t) {
        int col = (t << 4) + (lane & 15);
        float bv = bias[col];
        #pragma unroll
        for (int reg = 0; reg < 4; ++reg) {
            int n = rbase + reg;
            if (n < Nn) out[(size_t)n * 64 + col] = acc[t][reg] + bv;
        }
    }
}

extern "C" void kernel_launch(void* const* d_in, const int* in_sizes, int n_in,
                              void* d_out, int out_size, void* d_ws, size_t ws_size,
                              hipStream_t stream) {
    const float* features  = (const float*)d_in[0];
    const int*   receivers = (const int*)d_in[1];
    const float* relpos    = (const float*)d_in[2];
    const float* wsup      = (const float*)d_in[3];
    const int*   senders   = (const int*)d_in[4];
    const float* kern      = (const float*)d_in[5];
    const float* bias      = (const float*)d_in[6];
    float* out = (float*)d_out;

    const int Nn = in_sizes[0] / 64;
    const int E  = in_sizes[1];

    // ws: cnt[N] | rec[N*BUCKET*2 float4] | KfT | Abf
    char* wp = (char*)d_ws;
    size_t p = 0;
    auto take = [&](size_t bytes) { char* q = wp + p; p = (p + bytes + 255) & ~(size_t)255; return q; };
    int*    cnt = (int*)take((size_t)Nn * 4);
    float4* rec = (float4*)take((size_t)Nn * BUCKET * 32);
    u16*    KfT = (u16*)take((size_t)64 * 1024 * 2);
    u16*    Abf = (u16*)take((size_t)Nn * 1024 * 2);
    (void)ws_size;

    ascc_setup<<<dim3(256 + (Nn + 255) / 256), dim3(256), 0, stream>>>(KfT, kern, cnt, Nn);
    ascc_fillprep<<<dim3((E + 255) / 256), dim3(256), 0, stream>>>(
        rec, cnt, receivers, relpos, wsup, senders, E);
    ascc_accum<<<dim3((Nn + 3) / 4), dim3(256), 0, stream>>>(
        Abf, features, cnt, rec, Nn);
    ascc_mgemm<<<dim3((Nn + 63) / 64), dim3(256), 0, stream>>>(
        out, Abf, KfT, bias, Nn);
}